// Round 7
// baseline (295.984 us; speedup 1.0000x reference)
//
#include <hip/hip_runtime.h>

typedef __attribute__((ext_vector_type(8))) short short8;   // 8 x bf16 bits
typedef __attribute__((ext_vector_type(4))) float f32x4;

#define SPB 8    // samples per group
#define NG  8    // groups per block
// LDS element geometry (u16 units); all row strides EVEN so pair-reads are b32-aligned
#define XP_S   408              // xp sample stride (20*20 + 8)
#define A1_ROW 14               // 12 padded cols + 2 (even stride)
#define A1_CH  (12 * A1_ROW)    // 168
#define A1_S   2056             // 12*168 + 40 pad (bank spread)
#define A2_S   200              // per-sample a2 stride (192 used)
#define A3_S   34               // per-sample a3 stride (32 used; 34 avoids bank alias)

__device__ __forceinline__ float fast_tanh(float x) {
    float e = __builtin_amdgcn_exp2f(x * 2.8853900817779268f);
    return 1.0f - 2.0f * __builtin_amdgcn_rcpf(e + 1.0f);
}
__device__ __forceinline__ unsigned short f2bf(float f) {
    unsigned u = __builtin_bit_cast(unsigned, f);
    return (unsigned short)((u + 0x7FFF + ((u >> 16) & 1)) >> 16);
}

// k-slot permutation sigma for 5x5 patches (shared by A-pack and B-gather):
// slot m=8*hi+j -> pair P=m>>1 (clamped to 14), ky=P/3, q=P%3, c=2q+(m&1).
// Real iff c<5; c==5 and m>=30 are zero-weight garbage slots.

__global__ __launch_bounds__(256, 3) void lenet_mfma(
    const float* __restrict__ x,
    const float* __restrict__ w1, const float* __restrict__ b1,
    const float* __restrict__ w2, const float* __restrict__ b2,
    const float* __restrict__ w3, const float* __restrict__ b3,
    const float* __restrict__ ow, const float* __restrict__ ob,
    float* __restrict__ out)
{
    __shared__ __attribute__((aligned(16))) unsigned short xp[SPB * XP_S];
    __shared__ __attribute__((aligned(16))) unsigned short a1[SPB * A1_S];
    __shared__ __attribute__((aligned(16))) unsigned short a2[16 * A2_S];  // [sample][k]
    __shared__ __attribute__((aligned(16))) unsigned short a3[16 * A3_S];  // [sample][unit]
    __shared__ float b1s[768], b2s[192], b3s[32], obs[16];

    const int t = threadIdx.x;
    const int lane = t & 63, wv = t >> 6;
    const int hi = lane >> 4, col = lane & 15;

    // issue group-0 x loads first
    const float4* xg = (const float4*)(x + (size_t)blockIdx.x * NG * SPB * 256);
    float4 v0 = xg[2 * t], v1 = xg[2 * t + 1];

    // ---- per-lane pair offsets (u16 units) for the sigma gather ----
    int po1[4], po2[4];
    #pragma unroll
    for (int pp = 0; pp < 4; ++pp) {
        int P = 4 * hi + pp; if (P > 14) P = 14;
        int ky = P / 3, q = P - 3 * ky;
        po1[pp] = ky * 20 + 2 * q;
        po2[pp] = ky * A1_ROW + 2 * q;
    }

    // ---- build A-fragments in registers (predicated global loads, once/block) ----
    short8 aw1;
    #pragma unroll
    for (int j = 0; j < 8; ++j) {
        int m = 8 * hi + j; float val = 0.f;
        if (m < 30 && col < 12) {
            int P = m >> 1, ky = P / 3, q = P - 3 * ky, c = 2 * q + (m & 1);
            if (c < 5) val = w1[col * 25 + ky * 5 + c];
        }
        aw1[j] = (short)f2bf(val);
    }
    short8 aw2[12];
    #pragma unroll
    for (int ic = 0; ic < 12; ++ic) {
        #pragma unroll
        for (int j = 0; j < 8; ++j) {
            int m = 8 * hi + j; float val = 0.f;
            if (m < 30 && col < 12) {
                int P = m >> 1, ky = P / 3, q = P - 3 * ky, c = 2 * q + (m & 1);
                if (c < 5) {
                    int oc = col, icw;
                    if (oc < 4)      icw = (ic < 8) ? ic : -1;
                    else if (oc < 8) icw = (ic >= 4) ? ic - 4 : -1;
                    else             icw = (ic < 4) ? ic : ((ic >= 8) ? ic - 4 : -1);
                    if (icw >= 0) val = w2[(oc * 8 + icw) * 25 + ky * 5 + c];
                }
            }
            aw2[ic][j] = (short)f2bf(val);
        }
    }
    short8 aw3[6];                       // identity k-order (K=192 dense)
    {
        int unitB = (wv & 1) * 16 + col;
        #pragma unroll
        for (int kt = 0; kt < 6; ++kt)
            #pragma unroll
            for (int j = 0; j < 8; ++j) {
                int k = kt * 32 + 8 * hi + j;
                aw3[kt][j] = (short)f2bf((unitB < 30) ? w3[k * 30 + unitB] : 0.f);
            }
    }
    short8 awo;
    #pragma unroll
    for (int j = 0; j < 8; ++j) {
        int k = 8 * hi + j;
        awo[j] = (short)f2bf((col < 10 && k < 30) ? ow[k * 10 + col] : 0.f);
    }

    // ---- once per block: pads to -1 (bf16), a3 zero, biases ----
    {
        unsigned* xpw = (unsigned*)xp;
        for (int i = t; i < SPB * XP_S / 2; i += 256) xpw[i] = 0xBF80BF80u;
        unsigned* a1w = (unsigned*)a1;
        for (int i = t; i < SPB * A1_S / 2; i += 256) a1w[i] = 0xBF80BF80u;
        unsigned* a3w = (unsigned*)a3;
        for (int i = t; i < 16 * A3_S / 2; i += 256) a3w[i] = 0u;
        for (int i = t; i < 768; i += 256) b1s[i] = b1[i];
        if (t < 192) b2s[t] = b2[t];
        if (t < 32)  b3s[t] = (t < 30) ? b3[t] : 0.f;
        if (t < 16)  obs[t] = (t < 10) ? ob[t] : 0.f;
    }
    __syncthreads();

    const int q1 = 40 * (col >> 3) + 2 * (col & 7);   // H1 patch TL (u16)
    const int q2 = 28 * (col >> 2) + 2 * (col & 3);   // H2 patch TL (u16)
    const unsigned* xp32 = (const unsigned*)xp;
    const unsigned* a132 = (const unsigned*)a1;
    const unsigned* a232 = (const unsigned*)a2;
    const unsigned* a332 = (const unsigned*)a3;

    // ================= group loop =================
    #pragma unroll 1
    for (int g = 0; g < NG; ++g) {
        // ---- scatter x into padded LDS (bf16); same-wave producer/consumer ----
        {
            int s = t >> 5, r = (t & 31) >> 1, c0 = (t & 1) * 8;
            int base = s * XP_S + (2 + r) * 20 + (2 + c0);   // even
            unsigned* dst = (unsigned*)xp + (base >> 1);
            dst[0] = (unsigned)f2bf(v0.x) | ((unsigned)f2bf(v0.y) << 16);
            dst[1] = (unsigned)f2bf(v0.z) | ((unsigned)f2bf(v0.w) << 16);
            dst[2] = (unsigned)f2bf(v1.x) | ((unsigned)f2bf(v1.y) << 16);
            dst[3] = (unsigned)f2bf(v1.z) | ((unsigned)f2bf(v1.w) << 16);
        }
        if (g + 1 < NG) {   // prefetch next group's x
            const float4* xgn = (const float4*)(x + (size_t)(blockIdx.x * NG + g + 1) * SPB * 256);
            v0 = xgn[2 * t]; v1 = xgn[2 * t + 1];
        }

        // ---- H1: wave wv -> samples 2wv, 2wv+1; 4 pos-tiles each ----
        #pragma unroll
        for (int si = 0; si < 2; ++si) {
            int s = 2 * wv + si;
            int sbase = s * XP_S + q1;
            #pragma unroll
            for (int pt = 0; pt < 4; ++pt) {
                int base = (sbase + pt * 80) >> 1;
                short8 b;
                #pragma unroll
                for (int pp = 0; pp < 4; ++pp) {
                    unsigned r = xp32[base + (po1[pp] >> 1)];
                    b[2 * pp]     = (short)(r & 0xffff);
                    b[2 * pp + 1] = (short)(r >> 16);
                }
                f32x4 acc = __builtin_amdgcn_mfma_f32_16x16x32_bf16(
                    aw1, b, (f32x4){0.f, 0.f, 0.f, 0.f}, 0, 0, 0);
                int p = pt * 16 + col;
                int oy = p >> 3, ox = p & 7;
                int wbase = s * A1_S + (2 + oy) * A1_ROW + (2 + ox);
                #pragma unroll
                for (int jj = 0; jj < 4; ++jj) {
                    int oc = hi * 4 + jj;
                    if (oc < 12)
                        a1[wbase + oc * A1_CH] =
                            f2bf(fast_tanh(acc[jj] + b1s[oc * 64 + p]));
                }
            }
        }

        // ---- H2: 12 chained MFMAs per sample ----
        #pragma unroll
        for (int si = 0; si < 2; ++si) {
            int s = 2 * wv + si;
            int sbase = s * A1_S + q2;
            f32x4 acc = {0.f, 0.f, 0.f, 0.f};
            #pragma unroll
            for (int ic = 0; ic < 12; ++ic) {
                int base = (sbase + ic * A1_CH) >> 1;
                short8 b;
                #pragma unroll
                for (int pp = 0; pp < 4; ++pp) {
                    unsigned r = a132[base + (po2[pp] >> 1)];
                    b[2 * pp]     = (short)(r & 0xffff);
                    b[2 * pp + 1] = (short)(r >> 16);
                }
                acc = __builtin_amdgcn_mfma_f32_16x16x32_bf16(aw2[ic], b, acc, 0, 0, 0);
            }
            int sg = (g & 1) * 8 + s;
            #pragma unroll
            for (int jj = 0; jj < 4; ++jj) {
                int oc = hi * 4 + jj;
                if (oc < 12)
                    a2[sg * A2_S + oc * 16 + col] =
                        f2bf(fast_tanh(acc[jj] + b2s[oc * 16 + col]));
            }
        }

        // ---- every 2 groups: H3 (N=16) + out ----
        if (g & 1) {
            __syncthreads();   // B1: a2 (16 samples) complete
            if (wv < 2) {
                int rt = wv;
                f32x4 acc = {0.f, 0.f, 0.f, 0.f};
                #pragma unroll
                for (int kt = 0; kt < 6; ++kt) {
                    int base = (col * A2_S + kt * 32 + 8 * hi) >> 1;
                    short8 b;
                    #pragma unroll
                    for (int pp = 0; pp < 4; ++pp) {
                        unsigned r = a232[base + pp];
                        b[2 * pp]     = (short)(r & 0xffff);
                        b[2 * pp + 1] = (short)(r >> 16);
                    }
                    acc = __builtin_amdgcn_mfma_f32_16x16x32_bf16(aw3[kt], b, acc, 0, 0, 0);
                }
                #pragma unroll
                for (int jj = 0; jj < 4; ++jj) {
                    int unit = rt * 16 + hi * 4 + jj;
                    if (unit < 30)
                        a3[col * A3_S + unit] = f2bf(fast_tanh(acc[jj] + b3s[unit]));
                }
            }
            __syncthreads();   // B2: a3 cross-wave
            if (wv == 0) {
                int base = (col * A3_S + 8 * hi) >> 1;
                short8 b;
                #pragma unroll
                for (int pp = 0; pp < 4; ++pp) {
                    unsigned r = a332[base + pp];
                    b[2 * pp]     = (short)(r & 0xffff);
                    b[2 * pp + 1] = (short)(r >> 16);
                }
                f32x4 acc = __builtin_amdgcn_mfma_f32_16x16x32_bf16(
                    awo, b, (f32x4){0.f, 0.f, 0.f, 0.f}, 0, 0, 0);
                size_t sw = (size_t)blockIdx.x * NG * SPB + (g >> 1) * 16 + col;
                #pragma unroll
                for (int jj = 0; jj < 4; ++jj) {
                    int row = hi * 4 + jj;
                    if (row < 10)
                        out[sw * 10 + row] = fast_tanh(acc[jj] + obs[row]);
                }
            }
            __syncthreads();   // B3: a2/a3 free for next window
        }
    }
}

extern "C" void kernel_launch(void* const* d_in, const int* in_sizes, int n_in,
                              void* d_out, int out_size, void* d_ws, size_t ws_size,
                              hipStream_t stream) {
    const float* x  = (const float*)d_in[0];
    const float* w1 = (const float*)d_in[1];
    const float* b1 = (const float*)d_in[2];
    const float* w2 = (const float*)d_in[3];
    const float* b2 = (const float*)d_in[4];
    const float* w3 = (const float*)d_in[5];
    const float* b3 = (const float*)d_in[6];
    const float* ow = (const float*)d_in[7];
    const float* ob = (const float*)d_in[8];
    float* out = (float*)d_out;

    const int B = in_sizes[0] / 256;   // 65536 samples
    lenet_mfma<<<dim3(B / (SPB * NG)), dim3(256), 0, stream>>>(
        x, w1, b1, w2, b2, w3, b3, ow, ob, out);
}

// Round 8
// 111.720 us; speedup vs baseline: 2.6493x; 2.6493x over previous
//
#include <hip/hip_runtime.h>

typedef __attribute__((ext_vector_type(8))) short short8;   // 8 x bf16 bits
typedef __attribute__((ext_vector_type(4))) float f32x4;

#define SPB 4    // samples per group (1 per wave)
#define NG  8    // groups per block
// LDS element geometry (u16 units); row strides EVEN so pair-reads are b32-aligned
#define XP_S   400              // 20*20 padded input tile
#define A1_ROW 14               // 12 padded cols + 2 (even stride)
#define A1_CH  (12 * A1_ROW)    // 168
#define A1_S   (12 * A1_CH)     // 2016 per sample
#define A2_S   200              // per-sample a2 stride (192 used; *2B=400, 16B-aligned, bank-spread)
#define A3_S   40               // per-sample a3 stride (32 used; *2B=80, 16B-aligned)

__device__ __forceinline__ float fast_tanh(float x) {
    float e = __builtin_amdgcn_exp2f(x * 2.8853900817779268f);
    return 1.0f - 2.0f * __builtin_amdgcn_rcpf(e + 1.0f);
}
__device__ __forceinline__ unsigned short f2bf(float f) {
    unsigned u = __builtin_bit_cast(unsigned, f);
    return (unsigned short)((u + 0x7FFF + ((u >> 16) & 1)) >> 16);
}

// k-slot permutation sigma for 5x5 patches (shared by A-pack and B-gather):
// slot m=8*hi+j -> pair P=m>>1 (clamped to 14), ky=P/3, q=P%3, c=2q+(m&1).
// Real iff c<5; c==5 and m>=30 are zero-weight garbage slots.

__global__ __launch_bounds__(256, 3) void lenet_mfma(
    const float* __restrict__ x,
    const float* __restrict__ w1, const float* __restrict__ b1,
    const float* __restrict__ w2, const float* __restrict__ b2,
    const float* __restrict__ w3, const float* __restrict__ b3,
    const float* __restrict__ ow, const float* __restrict__ ob,
    float* __restrict__ out)
{
    __shared__ __attribute__((aligned(16))) unsigned short wf3[6144];       // w3 A-frags
    __shared__ __attribute__((aligned(16))) unsigned short xp[SPB * XP_S];
    __shared__ __attribute__((aligned(16))) unsigned short a1[SPB * A1_S];
    __shared__ __attribute__((aligned(16))) unsigned short a2[16 * A2_S];   // [sample][k]
    __shared__ __attribute__((aligned(16))) unsigned short a3[16 * A3_S];   // [sample][unit]
    __shared__ float b1s[768], b2s[192], b3s[32], obs[16];

    const int t = threadIdx.x;
    const int lane = t & 63, wv = t >> 6;
    const int hi = lane >> 4, col = lane & 15;

    // issue group-0 x load first (1 float4/thread; latency hides under setup)
    const float4* xg = (const float4*)(x + (size_t)blockIdx.x * NG * SPB * 256);
    float4 v0 = xg[t];

    // ---- per-lane pair offsets (u16 units) for the sigma gather ----
    int po1[4], po2[4];
    #pragma unroll
    for (int pp = 0; pp < 4; ++pp) {
        int P = 4 * hi + pp; if (P > 14) P = 14;
        int ky = P / 3, q = P - 3 * ky;
        po1[pp] = ky * 20 + 2 * q;
        po2[pp] = ky * A1_ROW + 2 * q;
    }

    // ---- aw1/aw2 in registers (52 VGPRs, proven r5/r6); sigma-packed ----
    short8 aw1;
    #pragma unroll
    for (int j = 0; j < 8; ++j) {
        int m = 8 * hi + j; float val = 0.f;
        if (m < 30 && col < 12) {
            int P = m >> 1, ky = P / 3, q = P - 3 * ky, c = 2 * q + (m & 1);
            if (c < 5) val = w1[col * 25 + ky * 5 + c];
        }
        aw1[j] = (short)f2bf(val);
    }
    short8 aw2[12];
    #pragma unroll
    for (int ic = 0; ic < 12; ++ic) {
        #pragma unroll
        for (int j = 0; j < 8; ++j) {
            int m = 8 * hi + j; float val = 0.f;
            if (m < 30 && col < 12) {
                int P = m >> 1, ky = P / 3, q = P - 3 * ky, c = 2 * q + (m & 1);
                if (c < 5) {
                    int oc = col, icw;
                    if (oc < 4)      icw = (ic < 8) ? ic : -1;
                    else if (oc < 8) icw = (ic >= 4) ? ic - 4 : -1;
                    else             icw = (ic < 4) ? ic : ((ic >= 8) ? ic - 4 : -1);
                    if (icw >= 0) val = w2[(oc * 8 + icw) * 25 + ky * 5 + c];
                }
            }
            aw2[ic][j] = (short)f2bf(val);
        }
    }
    short8 awo;   // out-layer A-frag (4 VGPRs), identity k-order
    #pragma unroll
    for (int j = 0; j < 8; ++j) {
        int k = 8 * hi + j;
        awo[j] = (short)f2bf((col < 10 && k < 30) ? ow[k * 10 + col] : 0.f);
    }

    // ---- wf3: w3 A-frags in LDS (once/block; avoids r7's register blowup) ----
    // entry e: fi=e>>6 (rt*6+kt), lane_e=e&63: A[unit][k]=w3[k*30+unit]
    for (int e = t; e < 768; e += 256) {
        int fi = e >> 6, le = e & 63;
        int rt = fi / 6, kt = fi - 6 * rt;
        int unit = rt * 16 + (le & 15);
        short8 v;
        #pragma unroll
        for (int j = 0; j < 8; ++j) {
            int k = kt * 32 + 8 * (le >> 4) + j;
            v[j] = (short)f2bf((unit < 30) ? w3[k * 30 + unit] : 0.f);
        }
        *((short8*)wf3 + e) = v;
    }

    // ---- fills: pad rings to -1 (persist; interiors rewritten每 group), a3 zero, biases ----
    {
        unsigned* xpw = (unsigned*)xp;
        for (int i = t; i < SPB * XP_S / 2; i += 256) xpw[i] = 0xBF80BF80u;
        unsigned* a1w = (unsigned*)a1;
        for (int i = t; i < SPB * A1_S / 2; i += 256) a1w[i] = 0xBF80BF80u;
        unsigned* a3w = (unsigned*)a3;
        for (int i = t; i < 16 * A3_S / 2; i += 256) a3w[i] = 0u;
        for (int i = t; i < 768; i += 256) b1s[i] = b1[i];
        if (t < 192) b2s[t] = b2[t];
        if (t < 32)  b3s[t] = (t < 30) ? b3[t] : 0.f;
        if (t < 16)  obs[t] = (t < 10) ? ob[t] : 0.f;
    }
    __syncthreads();

    const int q1 = 40 * (col >> 3) + 2 * (col & 7);   // H1 patch TL (u16)
    const int q2 = 28 * (col >> 2) + 2 * (col & 3);   // H2 patch TL (u16)
    const unsigned* xp32 = (const unsigned*)xp;
    const unsigned* a132 = (const unsigned*)a1;

    // ================= group loop =================
    #pragma unroll 1
    for (int g = 0; g < NG; ++g) {
        // ---- scatter own-sample x into padded LDS (same-wave prod/cons) ----
        {
            int r = (t >> 2) & 15, c4 = (t & 3) * 4;
            int base = wv * XP_S + (2 + r) * 20 + (2 + c4);   // even
            unsigned* dst = (unsigned*)xp + (base >> 1);
            dst[0] = (unsigned)f2bf(v0.x) | ((unsigned)f2bf(v0.y) << 16);
            dst[1] = (unsigned)f2bf(v0.z) | ((unsigned)f2bf(v0.w) << 16);
        }
        if (g + 1 < NG) v0 = xg[(g + 1) * 256 + t];   // prefetch next group

        // ---- H1: wave's sample; 4 pos-tile MFMAs ----
        {
            int sbase = wv * XP_S + q1;
            #pragma unroll
            for (int pt = 0; pt < 4; ++pt) {
                int base = (sbase + pt * 80) >> 1;
                short8 b;
                #pragma unroll
                for (int pp = 0; pp < 4; ++pp) {
                    unsigned r = xp32[base + (po1[pp] >> 1)];
                    b[2 * pp]     = (short)(r & 0xffff);
                    b[2 * pp + 1] = (short)(r >> 16);
                }
                f32x4 acc = __builtin_amdgcn_mfma_f32_16x16x32_bf16(
                    aw1, b, (f32x4){0.f, 0.f, 0.f, 0.f}, 0, 0, 0);
                int p = pt * 16 + col;
                int oy = p >> 3, ox = p & 7;
                int wbase = wv * A1_S + (2 + oy) * A1_ROW + (2 + ox);
                #pragma unroll
                for (int jj = 0; jj < 4; ++jj) {
                    int oc = hi * 4 + jj;
                    if (oc < 12)
                        a1[wbase + oc * A1_CH] =
                            f2bf(fast_tanh(acc[jj] + b1s[oc * 64 + p]));
                }
            }
        }

        // ---- H2: 12 chained MFMAs (one ic per K-tile) ----
        {
            int sbase = wv * A1_S + q2;
            f32x4 acc = {0.f, 0.f, 0.f, 0.f};
            #pragma unroll
            for (int ic = 0; ic < 12; ++ic) {
                int base = (sbase + ic * A1_CH) >> 1;
                short8 b;
                #pragma unroll
                for (int pp = 0; pp < 4; ++pp) {
                    unsigned r = a132[base + (po2[pp] >> 1)];
                    b[2 * pp]     = (short)(r & 0xffff);
                    b[2 * pp + 1] = (short)(r >> 16);
                }
                acc = __builtin_amdgcn_mfma_f32_16x16x32_bf16(aw2[ic], b, acc, 0, 0, 0);
            }
            int sg = (g & 3) * 4 + wv;
            #pragma unroll
            for (int jj = 0; jj < 4; ++jj) {
                int oc = hi * 4 + jj;
                if (oc < 12)
                    a2[sg * A2_S + oc * 16 + col] =
                        f2bf(fast_tanh(acc[jj] + b2s[oc * 16 + col]));
            }
        }

        // ---- every 4 groups: H3 (N=16 samples) + out ----
        if ((g & 3) == 3) {
            __syncthreads();   // B1: a2 (16 samples) complete
            if (wv < 2) {
                int rt = wv;
                f32x4 acc = {0.f, 0.f, 0.f, 0.f};
                #pragma unroll
                for (int kt = 0; kt < 6; ++kt) {
                    short8 a = *((const short8*)wf3 + (rt * 6 + kt) * 64 + lane);
                    short8 b = *(const short8*)&a2[col * A2_S + kt * 32 + 8 * hi];
                    acc = __builtin_amdgcn_mfma_f32_16x16x32_bf16(a, b, acc, 0, 0, 0);
                }
                #pragma unroll
                for (int jj = 0; jj < 4; ++jj) {
                    int unit = rt * 16 + hi * 4 + jj;
                    if (unit < 30)
                        a3[col * A3_S + unit] = f2bf(fast_tanh(acc[jj] + b3s[unit]));
                }
            }
            __syncthreads();   // B2: a3 cross-wave
            if (wv == 0) {
                short8 b = *(const short8*)&a3[col * A3_S + 8 * hi];
                f32x4 acc = __builtin_amdgcn_mfma_f32_16x16x32_bf16(
                    awo, b, (f32x4){0.f, 0.f, 0.f, 0.f}, 0, 0, 0);
                size_t sw = (size_t)blockIdx.x * (NG * SPB) + (g >> 2) * 16 + col;
                #pragma unroll
                for (int jj = 0; jj < 4; ++jj) {
                    int row = hi * 4 + jj;
                    if (row < 10)
                        out[sw * 10 + row] = fast_tanh(acc[jj] + obs[row]);
                }
            }
            __syncthreads();   // B3: a2/a3 free for next window
        }
    }
}

extern "C" void kernel_launch(void* const* d_in, const int* in_sizes, int n_in,
                              void* d_out, int out_size, void* d_ws, size_t ws_size,
                              hipStream_t stream) {
    const float* x  = (const float*)d_in[0];
    const float* w1 = (const float*)d_in[1];
    const float* b1 = (const float*)d_in[2];
    const float* w2 = (const float*)d_in[3];
    const float* b2 = (const float*)d_in[4];
    const float* w3 = (const float*)d_in[5];
    const float* b3 = (const float*)d_in[6];
    const float* ow = (const float*)d_in[7];
    const float* ob = (const float*)d_in[8];
    float* out = (float*)d_out;

    const int B = in_sizes[0] / 256;   // 65536 samples
    lenet_mfma<<<dim3(B / (SPB * NG)), dim3(256), 0, stream>>>(
        x, w1, b1, w2, b2, w3, b3, ow, ob, out);
}